// Round 14
// baseline (225.863 us; speedup 1.0000x reference)
//
#include <hip/hip_runtime.h>
#include <hip/hip_fp16.h>
#include <math.h>

// StressCapsuleLayer: capsule dynamic routing (3 iters), fused recompute design.
//   x [128][648][16] f32, W [648][32][32][16] f32 -> v [128][32][32] f32
//
//   pass0: c = 1/32 -> s0 -> v0 = squash(s0)            [f16 MFMA GEMM]
//   pass1: logit = <u_hat, v0>          -> softmax_j -> s1 -> v1
//   pass2: logit = <u, v0+v1> (linear)  -> softmax_j -> s2 -> v2 = output
//
// R14 (on R13's 41.8us/phase, 75% stalled, Occ 17%): phases restructured for
// 2 blocks/CU (cross-block stall overlap — 1 lockstep block/CU had nothing
// to fill its barrier/latency gaps):
//  - b-tile 32 -> 16 (grid NC*8 = 512 = 2/CU); B cols 16..31 zero (MFMA was
//    4.6% util, doubling matrix work is free).
//  - phase arena 139K -> 68K (W dbuf 64K + x dbuf 2K + lg 2K; epilogue 66.3K
//    reuse fits). 2 x 68K = 136K <= 160K.
//  - v: LDS (64K) -> 32 packed-f16 VGPRs/lane (wave needs only its 4 j's;
//    gathered once per kernel). Dot cost unchanged.
//  - no reg prefetch (staging inline after softmax; other block overlaps it);
//    lg[j][(b+j)&15] swizzle: write 16-distinct-banks, read 2-way (free).
//  - pass0 untouched (R13-validated).
// Spill detector: WRITE_SIZE >> ~34MB/pass (v-regs may push VGPR > 128).

#define N_IN 648
#define ELEMS 131072      // 128*32*32 output elements

// pass0 arena (unchanged from R13)
#define XF_OFF 65536
#define ARENA_P0 132608   // epilogue reuse [32][1036] f32

// phase arena: WF[2] @0/32768, X[2] @65536/+1024, LG @67584 (2KB)
#define PX_OFF 65536
#define PLG 67584
#define ARENA_PH 69632    // epilogue reuse [16][1036] f32 = 66304 fits

typedef __attribute__((ext_vector_type(8))) _Float16 f16x8;
typedef __attribute__((ext_vector_type(16))) float f32x16;

union F16U { uint4 u; f16x8 f; };
union HU { __half h; unsigned short us; };

__device__ __forceinline__ unsigned pkh(float a, float b) {
  HU x, y; x.h = __float2half(a); y.h = __float2half(b);
  return (unsigned)x.us | ((unsigned)y.us << 16);
}
__device__ __forceinline__ float h2f(unsigned short u) {
  HU x; x.us = u; return __half2float(x.h);
}

// cvt one W row (16 f32 in r[0..3]) to f16, write its two frag slots:
// (d,h=0) = i0..7 at jS*1024 + d*16; (d,h=1) = i8..15 at +512.
__device__ __forceinline__ void writeW(char* wbuf, int jS, int d, const float4* r) {
  uint4 h0, h1;
  h0.x = pkh(r[0].x, r[0].y); h0.y = pkh(r[0].z, r[0].w);
  h0.z = pkh(r[1].x, r[1].y); h0.w = pkh(r[1].z, r[1].w);
  h1.x = pkh(r[2].x, r[2].y); h1.y = pkh(r[2].z, r[2].w);
  h1.z = pkh(r[3].x, r[3].y); h1.w = pkh(r[3].z, r[3].w);
  *(uint4*)(wbuf + jS * 1024 + d * 16) = h0;
  *(uint4*)(wbuf + jS * 1024 + 512 + d * 16) = h1;
}
__device__ __forceinline__ void loadW(float4* r, const float* __restrict__ W,
                                      int n, int jS, int d) {
  const float4* rp = (const float4*)(W + (size_t)n * 16384 + jS * 512 + d * 16);
  r[0] = rp[0]; r[1] = rp[1]; r[2] = rp[2]; r[3] = rp[3];
}

// ---------------- pass 0 (R13-validated, untouched): 32-b tiles ----------
__device__ __forceinline__ void store_parts32(char* arena, float* __restrict__ parts,
                                              const f32x16* acc, float scale,
                                              int nchunk, int b0, int t) {
  const int w = t >> 6, l = t & 63;
  const int b32 = l & 31, half = l >> 5;
  __syncthreads();
#pragma unroll
  for (int q = 0; q < 4; ++q) {
    const int j = w * 4 + q;
#pragma unroll
    for (int g = 0; g < 4; ++g) {
      float4 v4;
      v4.x = acc[q][g * 4 + 0] * scale;
      v4.y = acc[q][g * 4 + 1] * scale;
      v4.z = acc[q][g * 4 + 2] * scale;
      v4.w = acc[q][g * 4 + 3] * scale;
      *(float4*)(arena + (b32 * 1036 + j * 32 + g * 8 + 4 * half) * 4) = v4;
    }
  }
  __syncthreads();
  float* pb = parts + (size_t)nchunk * ELEMS + (size_t)b0 * 1024;
  const int rb = t >> 4, c16 = t & 15;
#pragma unroll
  for (int q = 0; q < 16; ++q) {
    const int e4 = c16 + q * 16;
    const float4 v4 = *(const float4*)(arena + (rb * 1036 + e4 * 4) * 4);
    *(float4*)(pb + rb * 1024 + e4 * 4) = v4;
  }
}

__global__ __launch_bounds__(512, 1) void caps_pass0_mfma(
    const float* __restrict__ x, const float* __restrict__ W,
    float* __restrict__ parts, int NC)
{
  __shared__ __align__(16) char arena[ARENA_P0];
  const int t = threadIdx.x;
  const int w = t >> 6, l = t & 63;
  const int jS = t >> 4, m = t & 15;
  int nchunk, btile;
  if ((NC & 7) == 0) {
    const int r = blockIdx.x & 7;
    btile = (blockIdx.x >> 3) & 3;
    nchunk = (blockIdx.x >> 5) * 8 + r;
  } else { nchunk = blockIdx.x >> 2; btile = blockIdx.x & 3; }
  const int n0 = (N_IN * nchunk) / NC;
  const int n1 = (N_IN * (nchunk + 1)) / NC;
  const int b0 = btile * 32;

  f32x16 acc[4];
#pragma unroll
  for (int q = 0; q < 4; ++q) acc[q] = (f32x16)(0.0f);

  {
    float4 rA[4], rB[4];
    loadW(rA, W, n0, jS, m);
    loadW(rB, W, n0, jS, m + 16);
    writeW(arena, jS, m, rA);
    writeW(arena, jS, m + 16, rB);
    if (t < 64) {
      const float4* xp = (const float4*)(x + ((size_t)(b0 + (t & 31)) * N_IN + n0) * 16 + (t >> 5) * 8);
      *(float4*)(arena + XF_OFF + t * 16) = xp[0];
      *(float4*)(arena + XF_OFF + 1024 + t * 16) = xp[1];
    }
  }

  int cur = 0;
  for (int n = n0; n < n1; ++n) {
    __syncthreads();
    const char* wf = arena + cur * 32768;
    const char* xb = arena + XF_OFF + cur * 2048;
    char* nwf = arena + (cur ^ 1) * 32768;
    char* nxb = arena + XF_OFF + (cur ^ 1) * 2048;
    const bool more = (n + 1 < n1);

    float4 tA[4], tB[4], xt0, xt1;
    if (more) {
      loadW(tA, W, n + 1, jS, m);
      loadW(tB, W, n + 1, jS, m + 16);
      if (t < 64) {
        const float4* xp = (const float4*)(x + ((size_t)(b0 + (t & 31)) * N_IN + n + 1) * 16 + (t >> 5) * 8);
        xt0 = xp[0]; xt1 = xp[1];
      }
    }

    const float4 xw0 = *(const float4*)(xb + l * 16);
    const float4 xw1 = *(const float4*)(xb + 1024 + l * 16);
    F16U bf;
    bf.u = uint4{pkh(xw0.x, xw0.y), pkh(xw0.z, xw0.w),
                 pkh(xw1.x, xw1.y), pkh(xw1.z, xw1.w)};
#pragma unroll
    for (int q = 0; q < 4; ++q) {
      const int j = w * 4 + q;
      const f16x8 af = *(const f16x8*)(wf + j * 1024 + l * 16);
      acc[q] = __builtin_amdgcn_mfma_f32_32x32x16_f16(af, bf.f, acc[q], 0, 0, 0);
    }

    if (more) {
      writeW(nwf, jS, m, tA);
      writeW(nwf, jS, m + 16, tB);
      if (t < 64) {
        *(float4*)(nxb + t * 16) = xt0;
        *(float4*)(nxb + 1024 + t * 16) = xt1;
      }
    }
    cur ^= 1;
  }
  store_parts32(arena, parts, acc, 0.03125f, nchunk, b0, t);
}

// ------------- phases 1/2: 16-b tiles, 2 blocks/CU, v in registers ----------
__global__ __launch_bounds__(512, 2) void caps_phase_mfma(
    const float* __restrict__ x, const float* __restrict__ W,
    const float* __restrict__ v,      // v0 (phase1) or v0+v1 (phase2)
    float* __restrict__ parts, int NC)
{
  __shared__ __align__(16) char arena[ARENA_PH];
  const int t = threadIdx.x;
  const int w = t >> 6, l = t & 63;
  const int b32 = l & 31, half = l >> 5;
  const int b16 = b32 & 15;
  const bool bact = (b32 < 16);
  const int jS = t >> 4, m = t & 15;

  int nchunk, btile;
  if ((NC & 7) == 0) {            // all 8 b-tile sharers of a nchunk -> one XCD
    const int r = blockIdx.x & 7;
    btile = (blockIdx.x >> 3) & 7;
    nchunk = (blockIdx.x >> 6) * 8 + r;
  } else { nchunk = blockIdx.x >> 3; btile = blockIdx.x & 7; }
  const int n0 = (N_IN * nchunk) / NC;
  const int n1 = (N_IN * (nchunk + 1)) / NC;
  const int b0 = btile * 16;

  // ---- v gather ONCE into 32 packed-f16 regs: vw[q][p] covers k=2p,2p+1,
  // d(k) = (k&3) + 8*(k>>2) + 4*half (matches C-reg order of ut).
  unsigned vw[4][8];
  {
    const int bv = b0 + b16;      // clamped (lanes b32>=16 unused)
#pragma unroll
    for (int q = 0; q < 4; ++q) {
      const int j = w * 4 + q;
#pragma unroll
      for (int g = 0; g < 4; ++g) {
        const float4 g4 = *(const float4*)(v + (size_t)bv * 1024 + j * 32 + g * 8 + 4 * half);
        vw[q][2 * g]     = pkh(g4.x, g4.y);
        vw[q][2 * g + 1] = pkh(g4.z, g4.w);
      }
    }
  }

  // prologue: stage tile n0 into buffer 0
  {
    float4 rA[4], rB[4];
    loadW(rA, W, n0, jS, m);
    loadW(rB, W, n0, jS, m + 16);
    writeW(arena, jS, m, rA);
    writeW(arena, jS, m + 16, rB);
    if (t < 64) {                 // x: t = h*32 + b*2 + c
      const int c = t & 1, b = (t >> 1) & 15, h = t >> 5;
      *(float4*)(arena + PX_OFF + t * 16) =
          *(const float4*)(x + ((size_t)(b0 + b) * N_IN + n0) * 16 + h * 8 + c * 4);
    }
  }

  f32x16 acc[4];
#pragma unroll
  for (int q = 0; q < 4; ++q) acc[q] = (f32x16)(0.0f);

  int cur = 0;
  for (int n = n0; n < n1; ++n) {
    __syncthreads();                    // buf[cur] staged; lg free
    const char* wf = arena + cur * 32768;
    const char* xb = arena + PX_OFF + cur * 1024;
    char* nwf = arena + (cur ^ 1) * 32768;
    char* nxb = arena + PX_OFF + (cur ^ 1) * 1024;
    const bool more = (n + 1 < n1);

    // B frag: cols 16..31 zero
    float4 xw0 = float4{0.f, 0.f, 0.f, 0.f}, xw1 = xw0;
    if (bact) {
      xw0 = *(const float4*)(xb + (half * 32 + b16 * 2 + 0) * 16);
      xw1 = *(const float4*)(xb + (half * 32 + b16 * 2 + 1) * 16);
    }
    F16U bf;
    bf.u = uint4{pkh(xw0.x, xw0.y), pkh(xw0.z, xw0.w),
                 pkh(xw1.x, xw1.y), pkh(xw1.z, xw1.w)};

    // ---- logit pass: transient u per j, dot with v-regs, write lg ----
#pragma unroll
    for (int q = 0; q < 4; ++q) {
      const int j = w * 4 + q;
      const f16x8 af = *(const f16x8*)(wf + j * 1024 + l * 16);
      f32x16 ut = (f32x16)(0.0f);
      ut = __builtin_amdgcn_mfma_f32_32x32x16_f16(af, bf.f, ut, 0, 0, 0);
      float a = 0.f;
#pragma unroll
      for (int k = 0; k < 16; ++k) {
        const unsigned short us = (k & 1) ? (unsigned short)(vw[q][k >> 1] >> 16)
                                          : (unsigned short)(vw[q][k >> 1] & 0xFFFF);
        a = fmaf(ut[k], h2f(us), a);
      }
      a += __shfl_xor(a, 32);           // combine d-halves
      if (l < 16)                        // b = l; banks (b+j)&15 distinct
        *(float*)(arena + PLG + (j * 16 + ((l + j) & 15)) * 4) = a;
    }
    __syncthreads();                    // logits complete

    // ---- softmax over j per b: 512 thr = 32 j x 16 b, one round ----
    {
      const int jj = t & 31, b = t >> 5;
      float* slot = (float*)(arena + PLG + (jj * 16 + ((b + jj) & 15)) * 4);
      float lgv = *slot;
      float mx = lgv;
#pragma unroll
      for (int off = 16; off >= 1; off >>= 1) mx = fmaxf(mx, __shfl_xor(mx, off));
      const float e = __expf(lgv - mx);
      float Z = e;
#pragma unroll
      for (int off = 16; off >= 1; off >>= 1) Z += __shfl_xor(Z, off);
      *slot = e / Z;
    }

    // stage next tile inline (cross-block overlap hides the latency)
    if (more) {
      float4 rA[4], rB[4];
      loadW(rA, W, n + 1, jS, m);
      loadW(rB, W, n + 1, jS, m + 16);
      writeW(nwf, jS, m, rA);
      writeW(nwf, jS, m + 16, rB);
      if (t < 64) {
        const int c = t & 1, b = (t >> 1) & 15, h = t >> 5;
        *(float4*)(nxb + t * 16) =
            *(const float4*)(x + ((size_t)(b0 + b) * N_IN + n + 1) * 16 + h * 8 + c * 4);
      }
    }
    __syncthreads();                    // c visible

    // ---- s pass: B = f16(c_j * x); cols >=16 remain zero ----
#pragma unroll
    for (int q = 0; q < 4; ++q) {
      const int j = w * 4 + q;
      const float cj = *(const float*)(arena + PLG + (j * 16 + ((b16 + j) & 15)) * 4);
      F16U yf;
      yf.u = uint4{pkh(cj * xw0.x, cj * xw0.y), pkh(cj * xw0.z, cj * xw0.w),
                   pkh(cj * xw1.x, cj * xw1.y), pkh(cj * xw1.z, cj * xw1.w)};
      const f16x8 af = *(const f16x8*)(wf + j * 1024 + l * 16);
      acc[q] = __builtin_amdgcn_mfma_f32_32x32x16_f16(af, yf.f, acc[q], 0, 0, 0);
    }
    cur ^= 1;
  }

  // epilogue (16-b variant): scatter acc cols 0..15, read back coalesced
  __syncthreads();
#pragma unroll
  for (int q = 0; q < 4; ++q) {
    const int j = w * 4 + q;
    if (bact) {
#pragma unroll
      for (int g = 0; g < 4; ++g) {
        float4 v4;
        v4.x = acc[q][g * 4 + 0];
        v4.y = acc[q][g * 4 + 1];
        v4.z = acc[q][g * 4 + 2];
        v4.w = acc[q][g * 4 + 3];
        *(float4*)(arena + (b16 * 1036 + j * 32 + g * 8 + 4 * half) * 4) = v4;
      }
    }
  }
  __syncthreads();
  {
    float* pb = parts + (size_t)nchunk * ELEMS + (size_t)b0 * 1024;
    const int rb = t >> 5, c32 = t & 31;
#pragma unroll
    for (int q = 0; q < 8; ++q) {
      const int e4 = c32 + q * 32;
      const float4 v4 = *(const float4*)(arena + (rb * 1036 + e4 * 4) * 4);
      *(float4*)(pb + rb * 1024 + e4 * 4) = v4;
    }
  }
}

// stage B: sum NC partials, squash; optionally add previous v (vsum = v0+v1)
__global__ void reduce_squash(const float* __restrict__ parts, int NC,
                              float* __restrict__ out,
                              const float* __restrict__ addprev) {
  const int e = blockIdx.x * 256 + threadIdx.x;
  float s = 0.f;
  for (int c = 0; c < NC; ++c) s += parts[(size_t)c * ELEMS + e];
  float s2 = s * s;
#pragma unroll
  for (int off = 16; off >= 1; off >>= 1) s2 += __shfl_xor(s2, off);
  const float scale = (s2 / (1.0f + s2)) * rsqrtf(s2 + 1e-7f);
  const float val = s * scale;
  out[e] = addprev ? (addprev[e] + val) : val;
}

extern "C" void kernel_launch(void* const* d_in, const int* in_sizes, int n_in,
                              void* d_out, int out_size, void* d_ws, size_t ws_size,
                              hipStream_t stream) {
  const float* x = (const float*)d_in[0];
  const float* W = (const float*)d_in[1];
  float* out = (float*)d_out;

  float* v0 = (float*)d_ws;
  float* vsum = v0 + ELEMS;
  float* parts = vsum + ELEMS;

  int avail = 0;
  if (ws_size / 4 > 2 * (size_t)ELEMS)
    avail = (int)((ws_size / 4 - 2 * (size_t)ELEMS) / ELEMS);
  int NC = avail < 1 ? 1 : (avail > 64 ? 64 : avail);

  const dim3 blk(512);

  caps_pass0_mfma<<<dim3(NC * 4), blk, 0, stream>>>(x, W, parts, NC);
  reduce_squash<<<512, 256, 0, stream>>>(parts, NC, v0, nullptr);

  caps_phase_mfma<<<dim3(NC * 8), blk, 0, stream>>>(x, W, v0, parts, NC);
  reduce_squash<<<512, 256, 0, stream>>>(parts, NC, vsum, v0);  // v0 + v1

  caps_phase_mfma<<<dim3(NC * 8), blk, 0, stream>>>(x, W, vsum, parts, NC);
  reduce_squash<<<512, 256, 0, stream>>>(parts, NC, out, nullptr);
}

// Round 15
// 152.805 us; speedup vs baseline: 1.4781x; 1.4781x over previous
//
#include <hip/hip_runtime.h>
#include <hip/hip_fp16.h>
#include <math.h>

// StressCapsuleLayer: capsule dynamic routing (3 iters), fused recompute design.
//   x [128][648][16] f32, W [648][32][32][16] f32 -> v [128][32][32] f32
//
//   pass0: c = 1/32 -> s0 -> v0 = squash(s0)            [f16 MFMA GEMM]
//   pass1: logit = <u_hat, v0>          -> softmax_j -> s1 -> v1
//   pass2: logit = <u, v0+v1> (linear)  -> softmax_j -> s2 -> v2 = output
//
// R15: R13/R14 established the phase kernel is W-BYTE-FEED-BOUND: R13 read
// 4 btiles x 42.5MB = 170MB W/pass ~= 41.8us at ~6.5 B/cy/CU; R14's 8 btiles
// = 340MB -> 79us (2x, confirming). So:
//  1. W precomputed ONCE to f16 in the exact LDS frag layout (21.2MB in d_ws):
//     staging = pure 64B/thread copy (no cvt VALU), W traffic/pass halves.
//  2. R13 shape back (32-b tiles, grid NC*4); v in REGISTERS (R14-validated,
//     frees 64KB LDS); staging inline after softmax (peak regs ~120).
//  3. parts stored f16 (fits Wf16 in ws >= 38.8MB known; +~1e-3 err, 3.5x
//     margin under 1.36e-2).
// Spill detector: phase WRITE_SIZE >> ~17MB/pass.

#define N_IN 648
#define ELEMS 131072      // 128*32*32 output elements

// d_ws layout (bytes): v0 @0 (512KB), vsum @524288, wf16 @1048576 (21233664),
// parts(f16) @22282240 (NC x 262144)
#define WF16_OFF 1048576
#define PARTS_OFF 22282240

// LDS arena (both kernels): WF[2] @0/32768, X[2] @65536/67584 (2KB each),
// LG @69632 (4KB). Epilogue reuse [32][1036] f32 = 132608.
#define XF_OFF 65536
#define LG 69632
#define ARENA 132608

typedef __attribute__((ext_vector_type(8))) _Float16 f16x8;
typedef __attribute__((ext_vector_type(16))) float f32x16;

union F16U { uint4 u; f16x8 f; };
union HU { __half h; unsigned short us; };

__device__ __forceinline__ unsigned pkh(float a, float b) {
  HU x, y; x.h = __float2half(a); y.h = __float2half(b);
  return (unsigned)x.us | ((unsigned)y.us << 16);
}
__device__ __forceinline__ float h2f(unsigned short u) {
  HU x; x.us = u; return __half2float(x.h);
}

// cvt one W row (16 f32 in r[0..3]) to f16, write its two frag slots:
// (d,h=0) = i0..7 at jS*1024 + d*16; (d,h=1) = i8..15 at +512.
__device__ __forceinline__ void writeW(char* wbuf, int jS, int d, const float4* r) {
  uint4 h0, h1;
  h0.x = pkh(r[0].x, r[0].y); h0.y = pkh(r[0].z, r[0].w);
  h0.z = pkh(r[1].x, r[1].y); h0.w = pkh(r[1].z, r[1].w);
  h1.x = pkh(r[2].x, r[2].y); h1.y = pkh(r[2].z, r[2].w);
  h1.z = pkh(r[3].x, r[3].y); h1.w = pkh(r[3].z, r[3].w);
  *(uint4*)(wbuf + jS * 1024 + d * 16) = h0;
  *(uint4*)(wbuf + jS * 1024 + 512 + d * 16) = h1;
}
__device__ __forceinline__ void loadW(float4* r, const float* __restrict__ W,
                                      int n, int jS, int d) {
  const float4* rp = (const float4*)(W + (size_t)n * 16384 + jS * 512 + d * 16);
  r[0] = rp[0]; r[1] = rp[1]; r[2] = rp[2]; r[3] = rp[3];
}

// one-time: W f32 -> f16 frag-layout blocks in d_ws (32KB per n)
__global__ __launch_bounds__(512) void cvt_w_f16(const float* __restrict__ W,
                                                 char* __restrict__ wf) {
  const int n = blockIdx.x;
  const int t = threadIdx.x;
  const int jS = t >> 4, m = t & 15;
  float4 rA[4], rB[4];
  loadW(rA, W, n, jS, m);
  loadW(rB, W, n, jS, m + 16);
  char* dst = wf + (size_t)n * 32768;
  writeW(dst, jS, m, rA);
  writeW(dst, jS, m + 16, rB);
}

// stage one 32KB Wf16 tile: thread t copies 4 x 16B (offsets r*8192 + t*16)
__device__ __forceinline__ void copyW(char* dst, const char* __restrict__ src, int t) {
  uint4 c0 = *(const uint4*)(src + 0 * 8192 + t * 16);
  uint4 c1 = *(const uint4*)(src + 1 * 8192 + t * 16);
  uint4 c2 = *(const uint4*)(src + 2 * 8192 + t * 16);
  uint4 c3 = *(const uint4*)(src + 3 * 8192 + t * 16);
  *(uint4*)(dst + 0 * 8192 + t * 16) = c0;
  *(uint4*)(dst + 1 * 8192 + t * 16) = c1;
  *(uint4*)(dst + 2 * 8192 + t * 16) = c2;
  *(uint4*)(dst + 3 * 8192 + t * 16) = c3;
}

// epilogue: scatter acc (C layout: col=lane&31=b, d=(r&3)+8*(r>>2)+4*half)
// into arena [b][1036 f32], read back coalesced, store f16 parts.
__device__ __forceinline__ void store_parts(char* arena, __half* __restrict__ parts,
                                            const f32x16* acc, float scale,
                                            int nchunk, int b0, int t) {
  const int w = t >> 6, l = t & 63;
  const int b32 = l & 31, half = l >> 5;
  __syncthreads();
#pragma unroll
  for (int q = 0; q < 4; ++q) {
    const int j = w * 4 + q;
#pragma unroll
    for (int g = 0; g < 4; ++g) {
      float4 v4;
      v4.x = acc[q][g * 4 + 0] * scale;
      v4.y = acc[q][g * 4 + 1] * scale;
      v4.z = acc[q][g * 4 + 2] * scale;
      v4.w = acc[q][g * 4 + 3] * scale;
      *(float4*)(arena + (b32 * 1036 + j * 32 + g * 8 + 4 * half) * 4) = v4;
    }
  }
  __syncthreads();
  char* pb = (char*)(parts + (size_t)nchunk * ELEMS + (size_t)b0 * 1024);
  const int rb = t >> 4, c16 = t & 15;
#pragma unroll
  for (int q = 0; q < 8; ++q) {
    const int g8 = c16 + q * 16;               // 8-float group in row rb
    const float4 a = *(const float4*)(arena + (rb * 1036 + g8 * 8) * 4);
    const float4 b = *(const float4*)(arena + (rb * 1036 + g8 * 8 + 4) * 4);
    *(uint4*)(pb + rb * 2048 + g8 * 16) =
        uint4{pkh(a.x, a.y), pkh(a.z, a.w), pkh(b.x, b.y), pkh(b.z, b.w)};
  }
}

// XCD-aware decode: 4 btile-sharers of an n-chunk -> same XCD
__device__ __forceinline__ void decode_bid(int bid, int NC, int& nchunk, int& btile) {
  if ((NC & 7) == 0) {
    const int r = bid & 7;
    btile = (bid >> 3) & 3;
    nchunk = (bid >> 5) * 8 + r;
  } else {
    nchunk = bid >> 2;
    btile = bid & 3;
  }
}

// ---------------- pass 0: f16 MFMA GEMM over precomputed Wf16 ----------------
__global__ __launch_bounds__(512, 1) void caps_pass0_mfma(
    const float* __restrict__ x, const char* __restrict__ wf16,
    __half* __restrict__ parts, int NC)
{
  __shared__ __align__(16) char arena[ARENA];
  const int t = threadIdx.x;
  const int w = t >> 6, l = t & 63;
  int nchunk, btile;
  decode_bid(blockIdx.x, NC, nchunk, btile);
  const int n0 = (N_IN * nchunk) / NC;
  const int n1 = (N_IN * (nchunk + 1)) / NC;
  const int b0 = btile * 32;

  f32x16 acc[4];
#pragma unroll
  for (int q = 0; q < 4; ++q) acc[q] = (f32x16)(0.0f);

  // prologue: stage tile n0 into buffer 0
  copyW(arena, wf16 + (size_t)n0 * 32768, t);
  if (t < 64) {
    const float4* xp = (const float4*)(x + ((size_t)(b0 + (t & 31)) * N_IN + n0) * 16 + (t >> 5) * 8);
    *(float4*)(arena + XF_OFF + t * 16) = xp[0];
    *(float4*)(arena + XF_OFF + 1024 + t * 16) = xp[1];
  }

  int cur = 0;
  for (int n = n0; n < n1; ++n) {
    __syncthreads();
    const char* wf = arena + cur * 32768;
    const char* xb = arena + XF_OFF + cur * 2048;
    char* nwf = arena + (cur ^ 1) * 32768;
    char* nxb = arena + XF_OFF + (cur ^ 1) * 2048;
    const bool more = (n + 1 < n1);

    const float4 xw0 = *(const float4*)(xb + l * 16);
    const float4 xw1 = *(const float4*)(xb + 1024 + l * 16);
    F16U bf;
    bf.u = uint4{pkh(xw0.x, xw0.y), pkh(xw0.z, xw0.w),
                 pkh(xw1.x, xw1.y), pkh(xw1.z, xw1.w)};
#pragma unroll
    for (int q = 0; q < 4; ++q) {
      const int j = w * 4 + q;
      const f16x8 af = *(const f16x8*)(wf + j * 1024 + l * 16);
      acc[q] = __builtin_amdgcn_mfma_f32_32x32x16_f16(af, bf.f, acc[q], 0, 0, 0);
    }

    if (more) {
      copyW(nwf, wf16 + (size_t)(n + 1) * 32768, t);
      if (t < 64) {
        const float4* xp = (const float4*)(x + ((size_t)(b0 + (t & 31)) * N_IN + n + 1) * 16 + (t >> 5) * 8);
        *(float4*)(nxb + t * 16) = xp[0];
        *(float4*)(nxb + 1024 + t * 16) = xp[1];
      }
    }
    cur ^= 1;
  }
  store_parts(arena, parts, acc, 0.03125f, nchunk, b0, t);
}

// ------------- phases 1/2: v-in-regs, c folded into B, Wf16 copy-staged -----
__global__ __launch_bounds__(512, 1) void caps_phase_mfma(
    const float* __restrict__ x, const char* __restrict__ wf16,
    const float* __restrict__ v,      // v0 (phase1) or v0+v1 (phase2)
    __half* __restrict__ parts, int NC)
{
  __shared__ __align__(16) char arena[ARENA];
  const int t = threadIdx.x;
  const int w = t >> 6, l = t & 63;
  const int b32 = l & 31, half = l >> 5;
  int nchunk, btile;
  decode_bid(blockIdx.x, NC, nchunk, btile);
  const int n0 = (N_IN * nchunk) / NC;
  const int n1 = (N_IN * (nchunk + 1)) / NC;
  const int b0 = btile * 32;

  // ---- v gather ONCE into 32 packed-f16 regs: vw[q][p] covers k=2p,2p+1,
  // d(k) = (k&3) + 8*(k>>2) + 4*half (matches ut C-reg order). [R14-validated]
  unsigned vw[4][8];
  {
    const int bv = b0 + b32;
#pragma unroll
    for (int q = 0; q < 4; ++q) {
      const int j = w * 4 + q;
#pragma unroll
      for (int g = 0; g < 4; ++g) {
        const float4 g4 = *(const float4*)(v + (size_t)bv * 1024 + j * 32 + g * 8 + 4 * half);
        vw[q][2 * g]     = pkh(g4.x, g4.y);
        vw[q][2 * g + 1] = pkh(g4.z, g4.w);
      }
    }
  }

  // prologue: stage tile n0 into buffer 0
  copyW(arena, wf16 + (size_t)n0 * 32768, t);
  if (t < 64) {
    const float4* xp = (const float4*)(x + ((size_t)(b0 + (t & 31)) * N_IN + n0) * 16 + (t >> 5) * 8);
    *(float4*)(arena + XF_OFF + t * 16) = xp[0];
    *(float4*)(arena + XF_OFF + 1024 + t * 16) = xp[1];
  }

  f32x16 acc[4];
#pragma unroll
  for (int q = 0; q < 4; ++q) acc[q] = (f32x16)(0.0f);

  int cur = 0;
  for (int n = n0; n < n1; ++n) {
    __syncthreads();                    // buf[cur] staged; lg free
    const char* wf = arena + cur * 32768;
    const char* xb = arena + XF_OFF + cur * 2048;
    char* nwf = arena + (cur ^ 1) * 32768;
    char* nxb = arena + XF_OFF + (cur ^ 1) * 2048;
    const bool more = (n + 1 < n1);

    const float4 xw0 = *(const float4*)(xb + l * 16);
    const float4 xw1 = *(const float4*)(xb + 1024 + l * 16);
    F16U bf;
    bf.u = uint4{pkh(xw0.x, xw0.y), pkh(xw0.z, xw0.w),
                 pkh(xw1.x, xw1.y), pkh(xw1.z, xw1.w)};

    // ---- logit pass: transient u per j, dot with v-regs, write lg ----
#pragma unroll
    for (int q = 0; q < 4; ++q) {
      const int j = w * 4 + q;
      const f16x8 af = *(const f16x8*)(wf + j * 1024 + l * 16);
      f32x16 ut = (f32x16)(0.0f);
      ut = __builtin_amdgcn_mfma_f32_32x32x16_f16(af, bf.f, ut, 0, 0, 0);
      float a = 0.f;
#pragma unroll
      for (int k = 0; k < 16; ++k) {
        const unsigned short us = (k & 1) ? (unsigned short)(vw[q][k >> 1] >> 16)
                                          : (unsigned short)(vw[q][k >> 1] & 0xFFFF);
        a = fmaf(ut[k], h2f(us), a);
      }
      a += __shfl_xor(a, 32);           // combine d-halves
      if (l < 32)                        // banks (b^j)&31 distinct: conflict-free
        *(float*)(arena + LG + (j * 32 + ((b32 ^ j) & 31)) * 4) = a;
    }
    __syncthreads();                    // logits complete

    // ---- softmax over j per b (2 rounds of 16 b) ----
    {
      const int jj = t & 31;
#pragma unroll
      for (int r = 0; r < 2; ++r) {
        const int b = r * 16 + (t >> 5);
        float* slot = (float*)(arena + LG + (jj * 32 + ((b ^ jj) & 31)) * 4);
        float lgv = *slot;
        float mx = lgv;
#pragma unroll
        for (int off = 16; off >= 1; off >>= 1) mx = fmaxf(mx, __shfl_xor(mx, off));
        const float e = __expf(lgv - mx);
        float Z = e;
#pragma unroll
        for (int off = 16; off >= 1; off >>= 1) Z += __shfl_xor(Z, off);
        *slot = e / Z;
      }
    }

    // stage next tile inline (transient regs; latency exposed once per tile)
    if (more) {
      copyW(nwf, wf16 + (size_t)(n + 1) * 32768, t);
      if (t < 64) {
        const float4* xp = (const float4*)(x + ((size_t)(b0 + (t & 31)) * N_IN + n + 1) * 16 + (t >> 5) * 8);
        *(float4*)(nxb + t * 16) = xp[0];
        *(float4*)(nxb + 1024 + t * 16) = xp[1];
      }
    }
    __syncthreads();                    // c visible

    // ---- s pass: B = f16(c_j * x), accumulate into persistent acc ----
#pragma unroll
    for (int q = 0; q < 4; ++q) {
      const int j = w * 4 + q;
      const float cj = *(const float*)(arena + LG + (j * 32 + ((b32 ^ j) & 31)) * 4);
      F16U yf;
      yf.u = uint4{pkh(cj * xw0.x, cj * xw0.y), pkh(cj * xw0.z, cj * xw0.w),
                   pkh(cj * xw1.x, cj * xw1.y), pkh(cj * xw1.z, cj * xw1.w)};
      const f16x8 af = *(const f16x8*)(wf + j * 1024 + l * 16);
      acc[q] = __builtin_amdgcn_mfma_f32_32x32x16_f16(af, yf.f, acc[q], 0, 0, 0);
    }
    cur ^= 1;
  }
  store_parts(arena, parts, acc, 1.0f, nchunk, b0, t);
}

// stage B: sum NC f16 partials, squash; optionally add prev v (vsum = v0+v1)
__global__ void reduce_squash(const unsigned short* __restrict__ parts, int NC,
                              float* __restrict__ out,
                              const float* __restrict__ addprev) {
  const int e = blockIdx.x * 256 + threadIdx.x;
  float s = 0.f;
  for (int c = 0; c < NC; ++c) s += h2f(parts[(size_t)c * ELEMS + e]);
  float s2 = s * s;
#pragma unroll
  for (int off = 16; off >= 1; off >>= 1) s2 += __shfl_xor(s2, off);
  const float scale = (s2 / (1.0f + s2)) * rsqrtf(s2 + 1e-7f);
  const float val = s * scale;
  out[e] = addprev ? (addprev[e] + val) : val;
}

extern "C" void kernel_launch(void* const* d_in, const int* in_sizes, int n_in,
                              void* d_out, int out_size, void* d_ws, size_t ws_size,
                              hipStream_t stream) {
  const float* x = (const float*)d_in[0];
  const float* W = (const float*)d_in[1];
  float* out = (float*)d_out;

  float* v0 = (float*)d_ws;
  float* vsum = v0 + ELEMS;
  char* wf16 = (char*)d_ws + WF16_OFF;
  __half* parts = (__half*)((char*)d_ws + PARTS_OFF);

  // NC from remaining workspace (deterministic; ws >= 38.8MB known -> NC>=63)
  size_t rem = ws_size > (size_t)PARTS_OFF ? ws_size - PARTS_OFF : 0;
  int NC = (int)(rem / (ELEMS * 2));
  NC = NC < 1 ? 1 : (NC > 64 ? 64 : NC);

  const dim3 blk(512);

  cvt_w_f16<<<dim3(N_IN), blk, 0, stream>>>(W, wf16);

  caps_pass0_mfma<<<dim3(NC * 4), blk, 0, stream>>>(x, wf16, parts, NC);
  reduce_squash<<<512, 256, 0, stream>>>((const unsigned short*)parts, NC, v0, nullptr);

  caps_phase_mfma<<<dim3(NC * 4), blk, 0, stream>>>(x, wf16, v0, parts, NC);
  reduce_squash<<<512, 256, 0, stream>>>((const unsigned short*)parts, NC, vsum, v0);

  caps_phase_mfma<<<dim3(NC * 4), blk, 0, stream>>>(x, wf16, vsum, parts, NC);
  reduce_squash<<<512, 256, 0, stream>>>((const unsigned short*)parts, NC, out, nullptr);
}